// Round 3
// baseline (189.523 us; speedup 1.0000x reference)
//
#include <hip/hip_runtime.h>
#include <hip/hip_bf16.h>
#include <math.h>

#define B_  4
#define S_  2048
#define D_  512
#define H_  8
#define DK_ 64
#define M_  (B_ * S_)   // 8192

using bf16   = __bf16;
using bf16x4 = __bf16 __attribute__((ext_vector_type(4)));
using bf16x8 = __bf16 __attribute__((ext_vector_type(8)));
using f32x4  = float __attribute__((ext_vector_type(4)));

#define MFMA16(a, b, c) __builtin_amdgcn_mfma_f32_16x16x32_bf16((a), (b), (c), 0, 0, 0)
#define EXP2(x) exp2f(x)

typedef __attribute__((address_space(3))) void       lds_void;
typedef const __attribute__((address_space(1))) void gbl_void;

__device__ __forceinline__ void async16(const bf16* g, bf16* lds) {
    __builtin_amdgcn_global_load_lds((gbl_void*)g, (lds_void*)lds, 16, 0, 0);
}

__device__ __forceinline__ bf16x8 ldg8(const bf16* p) {
    return *reinterpret_cast<const bf16x8*>(p);
}

// Fragment-major layout for a [R x 512] matrix (rows = MFMA m/n dim, cols = K):
// chunk(g,k0,kk,t) holds rows g*64+t*16+{0..15}, cols k0*64+kk*32+{0..31};
// lane = (k_sub>>3)*16 + (row&15), 8 bf16 per lane. One ldg8 at base+lane*8 is
// a fully-coalesced 1 KB read in exact MFMA A/B fragment order.
__device__ __forceinline__ size_t fragbase(int g, int k0, int kk, int t) {
    return ((((size_t)(g * 8 + k0) * 2 + kk) * 4 + t) * 64) * 8;
}

// ---------------------------------------------------------------------------
// Fused f32->bf16 conversion + fragment-major re-layout for all 7 tensors.
// One WAVE per 1 KB fragment chunk: dst = base + c*512 + lane*8 is exactly
// linear (fully-coalesced 16 B/lane stores); src gathers 16 rows x 32 B
// (128 B-coalescible across the lg groups).
// ---------------------------------------------------------------------------
__global__ __launch_bounds__(256) void cvt_all(
    const float* __restrict__ x0, const float* __restrict__ x1, const float* __restrict__ x2,
    const float* __restrict__ w0, const float* __restrict__ w1,
    const float* __restrict__ w2, const float* __restrict__ w3,
    bf16* __restrict__ dst)
{
    const int w    = blockIdx.x * 4 + (threadIdx.x >> 6);  // wave id, 0..26623
    const int lane = threadIdx.x & 63;
    const int lg = lane >> 4, lc = lane & 15;
    const float* src;
    int c;
    size_t dbase;
    if (w < 24576) {                                       // X tensors: 3 x 8192 chunks
        const int seg = w >> 13;
        c = w & 8191;
        src = (seg == 0) ? x0 : (seg == 1) ? x1 : x2;
        dbase = (size_t)seg << 22;
    } else {                                               // W tensors: 4 x 512 chunks
        const int jj = w - 24576;
        const int seg = jj >> 9;
        c = jj & 511;
        src = (seg == 0) ? w0 : (seg == 1) ? w1 : (seg == 2) ? w2 : w3;
        dbase = ((size_t)3 << 22) + ((size_t)seg << 18);
    }
    // c = ((g*8+k0)*2+kk)*4+t  (matches fragbase ordering)
    const int g = c >> 6, k0 = (c >> 3) & 7, kk = (c >> 2) & 1, t = c & 3;
    const size_t soff = ((size_t)(g * 64 + t * 16 + lc) << 9) + k0 * 64 + kk * 32 + lg * 8;
    f32x4 a = *reinterpret_cast<const f32x4*>(src + soff);
    f32x4 b = *reinterpret_cast<const f32x4*>(src + soff + 4);
    bf16x8 r;
    #pragma unroll
    for (int j = 0; j < 4; ++j) { r[j] = (bf16)a[j]; r[j + 4] = (bf16)b[j]; }
    *reinterpret_cast<bf16x8*>(dst + dbase + ((size_t)c << 9) + (size_t)lane * 8) = r;
}

// ---------------------------------------------------------------------------
// QKV projection, LDS-FREE: both operands read as coalesced fragment loads
// straight from L2 (frag-major buffers). No __shared__, no barriers — the
// k-loop is pure load->MFMA, compiler-pipelined with vmcnt.
// z<2 (Q,K): A=W (m=d), B=X (n=s) -> C-regs along d, packed bf16x4 stores to
//   [z][bh][s][64]; z==0 folds 0.125*log2e. z==2 (V): A=X, B=W -> V^T store.
// Grid 768; XCD-aware decode keeps an X m-stripe on one XCD.
// ---------------------------------------------------------------------------
__global__ __launch_bounds__(256) void gemm_qkv(
    const bf16* __restrict__ Xf, const bf16* __restrict__ Wf,
    bf16* __restrict__ qkv)
{
    const int bx  = blockIdx.x;
    const int xcd = bx & 7;
    const int idx = bx >> 3;
    const int mt  = xcd + 8 * (idx & 7);       // 0..63: X 128-row tile
    const int rest = idx >> 3;
    const int nt  = rest & 3;                  // 0..3: W 128-row tile
    const int z   = rest >> 2;                 // 0..2

    const bf16* Xz = Xf + (size_t)z * M_ * D_;
    const bf16* Wz = Wf + (size_t)z * D_ * D_;
    const bool vz = (z == 2);
    const bf16* A  = vz ? Xz : Wz;             // MFMA-A operand (m rows)
    const bf16* Bm = vz ? Wz : Xz;             // MFMA-B operand (n rows)

    const int lane = threadIdx.x & 63;
    const int wave = threadIdx.x >> 6;
    const int lc = lane & 15;
    const int lg = lane >> 4;
    const int gA = (vz ? 2 * mt : 2 * nt) + (wave >> 1);
    const int gB = (vz ? 2 * nt : 2 * mt) + (wave & 1);

    f32x4 acc[4][4] = {};

    #pragma unroll
    for (int k0 = 0; k0 < 8; ++k0) {
        #pragma unroll
        for (int kk = 0; kk < 2; ++kk) {
            bf16x8 af[4], bfm[4];
            #pragma unroll
            for (int t = 0; t < 4; ++t)
                af[t] = ldg8(A + fragbase(gA, k0, kk, t) + (size_t)lane * 8);
            #pragma unroll
            for (int t = 0; t < 4; ++t)
                bfm[t] = ldg8(Bm + fragbase(gB, k0, kk, t) + (size_t)lane * 8);
            #pragma unroll
            for (int mi = 0; mi < 4; ++mi)
                #pragma unroll
                for (int ni = 0; ni < 4; ++ni)
                    acc[mi][ni] = MFMA16(af[mi], bfm[ni], acc[mi][ni]);
        }
    }

    if (z < 2) {
        bf16* Y = qkv + (size_t)z * M_ * D_;
        const float sc = (z == 0) ? 0.125f * 1.4426950408889634f : 1.0f;
        #pragma unroll
        for (int mi = 0; mi < 4; ++mi)
            #pragma unroll
            for (int ni = 0; ni < 4; ++ni) {
                const int d = gA * 64 + mi * 16 + lg * 4;
                const int s = gB * 64 + ni * 16 + lc;
                bf16x4 v;
                #pragma unroll
                for (int r = 0; r < 4; ++r) v[r] = (bf16)(acc[mi][ni][r] * sc);
                const size_t oidx =
                    ((((size_t)(s >> 11) * H_ + (d >> 6)) * S_
                      + (s & (S_ - 1))) << 6) + (d & 63);
                *reinterpret_cast<bf16x4*>(&Y[oidx]) = v;
            }
    } else {
        bf16* Y = qkv + (size_t)2 * M_ * D_;
        #pragma unroll
        for (int mi = 0; mi < 4; ++mi)
            #pragma unroll
            for (int ni = 0; ni < 4; ++ni) {
                const int s = gA * 64 + mi * 16 + lg * 4;
                const int d = gB * 64 + ni * 16 + lc;
                bf16x4 v;
                #pragma unroll
                for (int r = 0; r < 4; ++r) v[r] = (bf16)acc[mi][ni][r];
                const size_t oidx =
                    ((((size_t)(s >> 11)) * H_ + (d >> 6)) << 17)
                    + (size_t)(d & 63) * S_ + (s & (S_ - 1));
                *reinterpret_cast<bf16x4*>(&Y[oidx]) = v;
            }
    }
}

// ---------------------------------------------------------------------------
// Output projection, LDS-free: A=Wo frag (m=d), B=ctx frag (n=s).
// Block = 64 s-rows x 128 d-cols, 4 waves (each 64d x 64s via 2 a-tiles).
// Grid 512 (2 blocks/CU), XCD swizzle on the s-stripe.
// ---------------------------------------------------------------------------
__global__ __launch_bounds__(256) void gemm_out(
    const bf16* __restrict__ CtxF, const bf16* __restrict__ WoF,
    float* __restrict__ out)
{
    const int bx  = blockIdx.x;
    const int xcd = bx & 7;
    const int idx = bx >> 3;
    const int mt  = xcd + 8 * (idx & 15);      // 0..127: ctx 64-row s-group
    const int nt  = idx >> 4;                  // 0..3: Wo 128-row d-tile

    const int lane = threadIdx.x & 63;
    const int wave = threadIdx.x >> 6;
    const int lc = lane & 15;
    const int lg = lane >> 4;
    const int gA = 2 * nt + (wave >> 1);       // Wo 64-row group
    const int tA = (wave & 1) * 2;             // 2 d-tiles per wave
    const int gB = mt;                         // ctx s-group (shared by block)

    f32x4 acc[2][4] = {};

    #pragma unroll
    for (int k0 = 0; k0 < 8; ++k0) {
        #pragma unroll
        for (int kk = 0; kk < 2; ++kk) {
            bf16x8 af[2], bfm[4];
            #pragma unroll
            for (int ai = 0; ai < 2; ++ai)
                af[ai] = ldg8(WoF + fragbase(gA, k0, kk, tA + ai) + (size_t)lane * 8);
            #pragma unroll
            for (int t = 0; t < 4; ++t)
                bfm[t] = ldg8(CtxF + fragbase(gB, k0, kk, t) + (size_t)lane * 8);
            #pragma unroll
            for (int ai = 0; ai < 2; ++ai)
                #pragma unroll
                for (int ni = 0; ni < 4; ++ni)
                    acc[ai][ni] = MFMA16(af[ai], bfm[ni], acc[ai][ni]);
        }
    }

    #pragma unroll
    for (int ai = 0; ai < 2; ++ai)
        #pragma unroll
        for (int ni = 0; ni < 4; ++ni) {
            const int d = gA * 64 + (tA + ai) * 16 + lg * 4;
            const int s = gB * 64 + ni * 16 + lc;
            *reinterpret_cast<f32x4*>(&out[(size_t)s * D_ + d]) = acc[ai][ni];
        }
}

// ---------------------------------------------------------------------------
// Build the PV B-fragment IN REGISTERS from the QK^T score layout.
// Scores: lane(lg,lc) holds P[k=16t+4lg+r][q=lc] (r=0..3) per t.
// bf16-pack pairs into dwords, then one permlane16_swap per dword pair:
// dst.row[2k+1] <-> src.row[2k]. Result rows hold k-chunks in order
// sigma=[0,2,1,3]; V's LDS staging is source-permuted with the same sigma
// (T21: per-lane global src permutation, linear LDS, linear b128 reads).
// Must be the BUILTIN, not inline asm (hazard recognizer).
// ---------------------------------------------------------------------------
__device__ __forceinline__ bf16x8 pfrag(const f32x4 a, const f32x4 b) {
    union U4 { bf16x4 v; unsigned int u[2]; };
    U4 pa, pb;
    #pragma unroll
    for (int r = 0; r < 4; ++r) { pa.v[r] = (bf16)a[r]; pb.v[r] = (bf16)b[r]; }
    auto r0 = __builtin_amdgcn_permlane16_swap(pa.u[0], pb.u[0], false, false);
    auto r1 = __builtin_amdgcn_permlane16_swap(pa.u[1], pb.u[1], false, false);
    union U8 { unsigned int u[4]; bf16x8 v; } out;
    out.u[0] = r0[0]; out.u[1] = r1[0]; out.u[2] = r0[1]; out.u[3] = r1[1];
    return out.v;
}

// ---------------------------------------------------------------------------
// Causal flash attention (max-free softmax — scores bounded by construction).
// ONE 64-row q-tile per block (grid 1024 = 32 bh x 32 tiles): 4 blocks/CU =
// 4 waves/SIMD, double the old paired-tile occupancy — the counters showed a
// latency-bound kernel (MfmaUtil 12%, VALUBusy 40%, occupancy 19%, nothing
// saturated), so TLP is the lever, not per-step work. K/V streams per bh stay
// on one XCD (bx&7 fixed per bh) for L2 reuse. P never touches LDS
// (permlane16_swap fragments + sigma-permuted V staging). Epilogue writes ctx
// frag-major via per-wave LDS transpose reusing Ks.
// Q pre-scaled by 0.125*log2e (folded into its projection).
// ---------------------------------------------------------------------------
__global__ __launch_bounds__(256) void attn(
    const bf16* __restrict__ QKV, bf16* __restrict__ CtxF)
{
    const int bx = blockIdx.x;
    const int bh = (bx & 7) * 4 + ((bx >> 3) & 3);   // same-XCD bh grouping
    const int q  = bx >> 5;                           // 0..31: q-tile index
    const int b = bh >> 3, h = bh & 7;
    const size_t plane = (size_t)S_ * DK_;
    const bf16* Q  = QKV + (size_t)bh * plane;
    const bf16* Kp = QKV + (size_t)(B_ * H_) * plane + (size_t)bh * plane;
    const bf16* Vt = QKV + 2 * (size_t)(B_ * H_) * plane + (size_t)bh * plane;

    const int lane = threadIdx.x & 63;
    const int wave = threadIdx.x >> 6;
    const int lc = lane & 15;
    const int lg = lane >> 4;
    const int sg = ((lg & 1) << 1) | (lg >> 1);      // sigma(lg): swap 1<->2
    const int srow = wave * 16 + lc;
    const int mrow = wave * 16 + lc;     // q row within tile for this lane

    __shared__ bf16 Ks[2][64 * 64];
    __shared__ bf16 Vs[2][64 * 64];

    const int qR = q * 64 + mrow;
    bf16x8 qf0 = ldg8(Q + (size_t)qR * DK_ + lg * 8);
    bf16x8 qf1 = ldg8(Q + (size_t)qR * DK_ + 32 + lg * 8);

    f32x4 accO[4] = {};
    float li = 0.f;

    #pragma unroll
    for (int i = 0; i < 2; ++i) {        // prologue: stage tile 0 -> buf 0
        const int kc  = i * 4 + lg;
        const int kcv = i * 4 + sg;      // sigma-permuted V source (LDS linear)
        async16(Kp + (size_t)srow * DK_ + kc * 8,  Ks[0] + (i * 256 + wave * 64) * 8);
        async16(Vt + (size_t)srow * S_  + kcv * 8, Vs[0] + (i * 256 + wave * 64) * 8);
    }

    for (int j = 0; j <= q; ++j) {
        __syncthreads();                 // tile j staged; buf j-1 readers done
        if (j < q) {
            const int kn = (j + 1) * 64;
            bf16* kd = Ks[(j + 1) & 1];
            bf16* vd = Vs[(j + 1) & 1];
            #pragma unroll
            for (int i = 0; i < 2; ++i) {
                const int kc  = i * 4 + lg;
                const int kcv = i * 4 + sg;
                async16(Kp + (size_t)(kn + srow) * DK_ + kc * 8,
                        kd + (i * 256 + wave * 64) * 8);
                async16(Vt + (size_t)srow * S_ + kn + kcv * 8,
                        vd + (i * 256 + wave * 64) * 8);
            }
        }
        const bf16* ks = Ks[j & 1];
        const bf16* vs = Vs[j & 1];

        bf16x8 kf0[4], kf1[4], vf0[4], vf1[4];
        #pragma unroll
        for (int t = 0; t < 4; ++t) {
            kf0[t] = ldg8(&ks[(t * 64 + lane) * 8]);
            kf1[t] = ldg8(&ks[(256 + t * 64 + lane) * 8]);
            vf0[t] = ldg8(&vs[(t * 64 + lane) * 8]);
            vf1[t] = ldg8(&vs[(256 + t * 64 + lane) * 8]);
        }

        f32x4 st[4];
        #pragma unroll
        for (int t = 0; t < 4; ++t) {
            f32x4 zz = {};
            zz = MFMA16(kf0[t], qf0, zz);
            st[t] = MFMA16(kf1[t], qf1, zz);
        }
        float rs = 0.f;
        if (j == q) {                    // diagonal tile: causal mask
            #pragma unroll
            for (int t = 0; t < 4; ++t)
                #pragma unroll
                for (int r = 0; r < 4; ++r) {
                    const int kl = t * 16 + lg * 4 + r;
                    const float pv = EXP2((kl <= mrow) ? st[t][r] : -1e30f);
                    st[t][r] = pv;
                    rs += pv;
                }
        } else {
            #pragma unroll
            for (int t = 0; t < 4; ++t)
                #pragma unroll
                for (int r = 0; r < 4; ++r) {
                    const float pv = EXP2(st[t][r]);
                    st[t][r] = pv;
                    rs += pv;
                }
        }
        li += rs;

        const bf16x8 p0 = pfrag(st[0], st[1]);   // k 0..31  (sigma order)
        const bf16x8 p1 = pfrag(st[2], st[3]);   // k 32..63 (sigma order)

        #pragma unroll
        for (int t = 0; t < 4; ++t) {
            accO[t] = MFMA16(vf0[t], p0, accO[t]);
            accO[t] = MFMA16(vf1[t], p1, accO[t]);
        }
    }

    // ---- epilogue: frag-major ctx via per-wave LDS transpose ---------------
    li += __shfl_xor(li, 16); li += __shfl_xor(li, 32);
    const float rl = 1.0f / li;
    __syncthreads();                     // all K/V reads done; reuse Ks
    bf16* T = &Ks[0][0] + wave * 1280;   // 16 x 72 (padded) transpose buffer

    #pragma unroll
    for (int t = 0; t < 4; ++t) {
        bf16x4 ov;
        #pragma unroll
        for (int r = 0; r < 4; ++r) ov[r] = (bf16)(accO[t][r] * rl);
        *reinterpret_cast<bf16x4*>(&T[lc * 72 + t * 16 + lg * 4]) = ov;
    }
    // wave-synchronous LDS: compiler inserts lgkmcnt before these reads
    #pragma unroll
    for (int kk = 0; kk < 2; ++kk) {
        bf16x8 o8 = ldg8(&T[lc * 72 + kk * 32 + lg * 8]);
        *reinterpret_cast<bf16x8*>(
            &CtxF[fragbase(b * 32 + q, h, kk, wave) + (size_t)lane * 8]) = o8;
    }
}

extern "C" void kernel_launch(void* const* d_in, const int* in_sizes, int n_in,
                              void* d_out, int out_size, void* d_ws, size_t ws_size,
                              hipStream_t stream)
{
    float* out = (float*)d_out;

    bf16* Xf   = (bf16*)d_ws;                         // [3][M_*D_] frag-major
    bf16* Wf   = Xf + (size_t)3 * M_ * D_;            // [4][D_*D_] frag-major
    bf16* qkv  = Wf + (size_t)4 * D_ * D_;            // Q,K [bh][s][64]; V^T [bh][d][s]
    bf16* ctxF = qkv + (size_t)3 * M_ * D_;           // [M_*D_] frag-major

    cvt_all<<<6656, 256, 0, stream>>>(
        (const float*)d_in[0], (const float*)d_in[1], (const float*)d_in[2],
        (const float*)d_in[3], (const float*)d_in[4], (const float*)d_in[5],
        (const float*)d_in[6], Xf);

    gemm_qkv<<<dim3(768), 256, 0, stream>>>(Xf, Wf, qkv);
    attn<<<dim3(1024), 256, 0, stream>>>(qkv, ctxF);
    gemm_out<<<dim3(512), 256, 0, stream>>>(ctxF, Wf + (size_t)3 * D_ * D_, out);
}

// Round 4
// 185.348 us; speedup vs baseline: 1.0225x; 1.0225x over previous
//
#include <hip/hip_runtime.h>
#include <hip/hip_bf16.h>
#include <math.h>

#define B_  4
#define S_  2048
#define D_  512
#define H_  8
#define DK_ 64
#define M_  (B_ * S_)   // 8192

using bf16   = __bf16;
using bf16x4 = __bf16 __attribute__((ext_vector_type(4)));
using bf16x8 = __bf16 __attribute__((ext_vector_type(8)));
using f32x4  = float __attribute__((ext_vector_type(4)));

#define MFMA16(a, b, c) __builtin_amdgcn_mfma_f32_16x16x32_bf16((a), (b), (c), 0, 0, 0)
#define EXP2(x) exp2f(x)

typedef __attribute__((address_space(3))) void       lds_void;
typedef const __attribute__((address_space(1))) void gbl_void;

__device__ __forceinline__ void async16(const bf16* g, bf16* lds) {
    __builtin_amdgcn_global_load_lds((gbl_void*)g, (lds_void*)lds, 16, 0, 0);
}

__device__ __forceinline__ bf16x8 ldg8(const bf16* p) {
    return *reinterpret_cast<const bf16x8*>(p);
}

// Fragment-major layout for a [R x 512] matrix (rows = MFMA m/n dim, cols = K):
// chunk(g,k0,kk,t) holds rows g*64+t*16+{0..15}, cols k0*64+kk*32+{0..31};
// lane = (k_sub>>3)*16 + (row&15), 8 bf16 per lane. One ldg8 at base+lane*8 is
// a fully-coalesced 1 KB read in exact MFMA A/B fragment order.
__device__ __forceinline__ size_t fragbase(int g, int k0, int kk, int t) {
    return ((((size_t)(g * 8 + k0) * 2 + kk) * 4 + t) * 64) * 8;
}

// ---------------------------------------------------------------------------
// Fused f32->bf16 conversion + fragment-major re-layout for all 7 tensors.
// One WAVE per 1 KB fragment chunk: dst = base + c*512 + lane*8 is exactly
// linear (fully-coalesced 16 B/lane stores); src gathers 16 rows x 32 B
// (128 B-coalescible across the lg groups).
// ---------------------------------------------------------------------------
__global__ __launch_bounds__(256) void cvt_all(
    const float* __restrict__ x0, const float* __restrict__ x1, const float* __restrict__ x2,
    const float* __restrict__ w0, const float* __restrict__ w1,
    const float* __restrict__ w2, const float* __restrict__ w3,
    bf16* __restrict__ dst)
{
    const int w    = blockIdx.x * 4 + (threadIdx.x >> 6);  // wave id, 0..26623
    const int lane = threadIdx.x & 63;
    const int lg = lane >> 4, lc = lane & 15;
    const float* src;
    int c;
    size_t dbase;
    if (w < 24576) {                                       // X tensors: 3 x 8192 chunks
        const int seg = w >> 13;
        c = w & 8191;
        src = (seg == 0) ? x0 : (seg == 1) ? x1 : x2;
        dbase = (size_t)seg << 22;
    } else {                                               // W tensors: 4 x 512 chunks
        const int jj = w - 24576;
        const int seg = jj >> 9;
        c = jj & 511;
        src = (seg == 0) ? w0 : (seg == 1) ? w1 : (seg == 2) ? w2 : w3;
        dbase = ((size_t)3 << 22) + ((size_t)seg << 18);
    }
    // c = ((g*8+k0)*2+kk)*4+t  (matches fragbase ordering)
    const int g = c >> 6, k0 = (c >> 3) & 7, kk = (c >> 2) & 1, t = c & 3;
    const size_t soff = ((size_t)(g * 64 + t * 16 + lc) << 9) + k0 * 64 + kk * 32 + lg * 8;
    f32x4 a = *reinterpret_cast<const f32x4*>(src + soff);
    f32x4 b = *reinterpret_cast<const f32x4*>(src + soff + 4);
    bf16x8 r;
    #pragma unroll
    for (int j = 0; j < 4; ++j) { r[j] = (bf16)a[j]; r[j + 4] = (bf16)b[j]; }
    *reinterpret_cast<bf16x8*>(dst + dbase + ((size_t)c << 9) + (size_t)lane * 8) = r;
}

// ---------------------------------------------------------------------------
// QKV projection, LDS-FREE: both operands read as coalesced fragment loads
// straight from L2 (frag-major buffers). No __shared__, no barriers — the
// k-loop is pure load->MFMA, compiler-pipelined with vmcnt.
// z<2 (Q,K): A=W (m=d), B=X (n=s) -> C-regs along d, packed bf16x4 stores to
//   [z][bh][s][64]; z==0 folds 0.125*log2e. z==2 (V): A=X, B=W -> V^T store.
// Grid 768; XCD-aware decode keeps an X m-stripe on one XCD.
// ---------------------------------------------------------------------------
__global__ __launch_bounds__(256) void gemm_qkv(
    const bf16* __restrict__ Xf, const bf16* __restrict__ Wf,
    bf16* __restrict__ qkv)
{
    const int bx  = blockIdx.x;
    const int xcd = bx & 7;
    const int idx = bx >> 3;
    const int mt  = xcd + 8 * (idx & 7);       // 0..63: X 128-row tile
    const int rest = idx >> 3;
    const int nt  = rest & 3;                  // 0..3: W 128-row tile
    const int z   = rest >> 2;                 // 0..2

    const bf16* Xz = Xf + (size_t)z * M_ * D_;
    const bf16* Wz = Wf + (size_t)z * D_ * D_;
    const bool vz = (z == 2);
    const bf16* A  = vz ? Xz : Wz;             // MFMA-A operand (m rows)
    const bf16* Bm = vz ? Wz : Xz;             // MFMA-B operand (n rows)

    const int lane = threadIdx.x & 63;
    const int wave = threadIdx.x >> 6;
    const int lc = lane & 15;
    const int lg = lane >> 4;
    const int gA = (vz ? 2 * mt : 2 * nt) + (wave >> 1);
    const int gB = (vz ? 2 * nt : 2 * mt) + (wave & 1);

    f32x4 acc[4][4] = {};

    #pragma unroll
    for (int k0 = 0; k0 < 8; ++k0) {
        #pragma unroll
        for (int kk = 0; kk < 2; ++kk) {
            bf16x8 af[4], bfm[4];
            #pragma unroll
            for (int t = 0; t < 4; ++t)
                af[t] = ldg8(A + fragbase(gA, k0, kk, t) + (size_t)lane * 8);
            #pragma unroll
            for (int t = 0; t < 4; ++t)
                bfm[t] = ldg8(Bm + fragbase(gB, k0, kk, t) + (size_t)lane * 8);
            #pragma unroll
            for (int mi = 0; mi < 4; ++mi)
                #pragma unroll
                for (int ni = 0; ni < 4; ++ni)
                    acc[mi][ni] = MFMA16(af[mi], bfm[ni], acc[mi][ni]);
        }
    }

    if (z < 2) {
        bf16* Y = qkv + (size_t)z * M_ * D_;
        const float sc = (z == 0) ? 0.125f * 1.4426950408889634f : 1.0f;
        #pragma unroll
        for (int mi = 0; mi < 4; ++mi)
            #pragma unroll
            for (int ni = 0; ni < 4; ++ni) {
                const int d = gA * 64 + mi * 16 + lg * 4;
                const int s = gB * 64 + ni * 16 + lc;
                bf16x4 v;
                #pragma unroll
                for (int r = 0; r < 4; ++r) v[r] = (bf16)(acc[mi][ni][r] * sc);
                const size_t oidx =
                    ((((size_t)(s >> 11) * H_ + (d >> 6)) * S_
                      + (s & (S_ - 1))) << 6) + (d & 63);
                *reinterpret_cast<bf16x4*>(&Y[oidx]) = v;
            }
    } else {
        bf16* Y = qkv + (size_t)2 * M_ * D_;
        #pragma unroll
        for (int mi = 0; mi < 4; ++mi)
            #pragma unroll
            for (int ni = 0; ni < 4; ++ni) {
                const int s = gA * 64 + mi * 16 + lg * 4;
                const int d = gB * 64 + ni * 16 + lc;
                bf16x4 v;
                #pragma unroll
                for (int r = 0; r < 4; ++r) v[r] = (bf16)acc[mi][ni][r];
                const size_t oidx =
                    ((((size_t)(s >> 11)) * H_ + (d >> 6)) << 17)
                    + (size_t)(d & 63) * S_ + (s & (S_ - 1));
                *reinterpret_cast<bf16x4*>(&Y[oidx]) = v;
            }
    }
}

// ---------------------------------------------------------------------------
// Output projection, LDS-free: A=Wo frag (m=d), B=ctx frag (n=s).
// Block = 64 s-rows x 128 d-cols, 4 waves (each 64d x 64s via 2 a-tiles).
// Grid 512 (2 blocks/CU), XCD swizzle on the s-stripe.
// ---------------------------------------------------------------------------
__global__ __launch_bounds__(256) void gemm_out(
    const bf16* __restrict__ CtxF, const bf16* __restrict__ WoF,
    float* __restrict__ out)
{
    const int bx  = blockIdx.x;
    const int xcd = bx & 7;
    const int idx = bx >> 3;
    const int mt  = xcd + 8 * (idx & 15);      // 0..127: ctx 64-row s-group
    const int nt  = idx >> 4;                  // 0..3: Wo 128-row d-tile

    const int lane = threadIdx.x & 63;
    const int wave = threadIdx.x >> 6;
    const int lc = lane & 15;
    const int lg = lane >> 4;
    const int gA = 2 * nt + (wave >> 1);       // Wo 64-row group
    const int tA = (wave & 1) * 2;             // 2 d-tiles per wave
    const int gB = mt;                         // ctx s-group (shared by block)

    f32x4 acc[2][4] = {};

    #pragma unroll
    for (int k0 = 0; k0 < 8; ++k0) {
        #pragma unroll
        for (int kk = 0; kk < 2; ++kk) {
            bf16x8 af[2], bfm[4];
            #pragma unroll
            for (int ai = 0; ai < 2; ++ai)
                af[ai] = ldg8(WoF + fragbase(gA, k0, kk, tA + ai) + (size_t)lane * 8);
            #pragma unroll
            for (int t = 0; t < 4; ++t)
                bfm[t] = ldg8(CtxF + fragbase(gB, k0, kk, t) + (size_t)lane * 8);
            #pragma unroll
            for (int ai = 0; ai < 2; ++ai)
                #pragma unroll
                for (int ni = 0; ni < 4; ++ni)
                    acc[ai][ni] = MFMA16(af[ai], bfm[ni], acc[ai][ni]);
        }
    }

    #pragma unroll
    for (int ai = 0; ai < 2; ++ai)
        #pragma unroll
        for (int ni = 0; ni < 4; ++ni) {
            const int d = gA * 64 + (tA + ai) * 16 + lg * 4;
            const int s = gB * 64 + ni * 16 + lc;
            *reinterpret_cast<f32x4*>(&out[(size_t)s * D_ + d]) = acc[ai][ni];
        }
}

// ---------------------------------------------------------------------------
// Build the PV B-fragment IN REGISTERS from the QK^T score layout.
// Scores: lane(lg,lc) holds P[k=16t+4lg+r][q=lc] (r=0..3) per t.
// bf16-pack pairs into dwords, then one permlane16_swap per dword pair:
// dst.row[2k+1] <-> src.row[2k]. Result rows hold k-chunks in order
// sigma=[0,2,1,3]; V's LDS staging is source-permuted with the same sigma
// (T21: per-lane global src permutation, linear LDS, linear b128 reads).
// Must be the BUILTIN, not inline asm (hazard recognizer).
// ---------------------------------------------------------------------------
__device__ __forceinline__ bf16x8 pfrag(const f32x4 a, const f32x4 b) {
    union U4 { bf16x4 v; unsigned int u[2]; };
    U4 pa, pb;
    #pragma unroll
    for (int r = 0; r < 4; ++r) { pa.v[r] = (bf16)a[r]; pb.v[r] = (bf16)b[r]; }
    auto r0 = __builtin_amdgcn_permlane16_swap(pa.u[0], pb.u[0], false, false);
    auto r1 = __builtin_amdgcn_permlane16_swap(pa.u[1], pb.u[1], false, false);
    union U8 { unsigned int u[4]; bf16x8 v; } out;
    out.u[0] = r0[0]; out.u[1] = r1[0]; out.u[2] = r0[1]; out.u[3] = r1[1];
    return out.v;
}

// ---------------------------------------------------------------------------
// Causal flash attention (max-free softmax — scores bounded by construction).
// Paired anti-diagonal q-tiles (lo=pi, hi=31-pi) per block: uniform 33 step
// calls, grid 512. r2/r3 showed duration == max-iteration-count x ~4k cycles
// regardless of grid: the per-iter __syncthreads drained vmcnt(0), exposing
// the full global->LDS round trip every iteration (the m97-structure stall).
// FIX (T3/T4): 4-deep K/V ring (64 KB LDS), raw s_barrier + counted
// s_waitcnt vmcnt(8) — two prefetched tiles stay in flight across every
// barrier; the drain never happens. Buffer-reuse safety: stage(j+3) writes
// buf (j-1)&3, whose readers all passed this iteration's barrier.
// P never touches LDS (permlane16_swap fragments + sigma-permuted V staging).
// Q pre-scaled by 0.125*log2e (folded into its projection).
// ---------------------------------------------------------------------------
__global__ __launch_bounds__(256) void attn(
    const bf16* __restrict__ QKV, bf16* __restrict__ CtxF)
{
    const int bx = blockIdx.x;
    const int bh = (bx & 7) * 4 + ((bx >> 3) & 3);   // same-XCD bh grouping
    const int pi = bx >> 5;                           // 0..15
    const int b = bh >> 3, h = bh & 7;
    const size_t plane = (size_t)S_ * DK_;
    const bf16* Q  = QKV + (size_t)bh * plane;
    const bf16* Kp = QKV + (size_t)(B_ * H_) * plane + (size_t)bh * plane;
    const bf16* Vt = QKV + 2 * (size_t)(B_ * H_) * plane + (size_t)bh * plane;

    const int lane = threadIdx.x & 63;
    const int wave = threadIdx.x >> 6;
    const int lc = lane & 15;
    const int lg = lane >> 4;
    const int sg = ((lg & 1) << 1) | (lg >> 1);      // sigma(lg): swap 1<->2
    const int srow = wave * 16 + lc;
    const int mrow = wave * 16 + lc;     // q row within tile for this lane

    __shared__ bf16 Ks[4][64 * 64];      // 4-deep ring, 32 KB
    __shared__ bf16 Vs[4][64 * 64];      // 4-deep ring, 32 KB

    const int lo = pi;
    const int hi = 31 - pi;              // hi >= 16 always

    const int qL = lo * 64 + mrow;
    const int qH = hi * 64 + mrow;
    bf16x8 qfL0 = ldg8(Q + (size_t)qL * DK_ + lg * 8);
    bf16x8 qfL1 = ldg8(Q + (size_t)qL * DK_ + 32 + lg * 8);
    bf16x8 qfH0 = ldg8(Q + (size_t)qH * DK_ + lg * 8);
    bf16x8 qfH1 = ldg8(Q + (size_t)qH * DK_ + 32 + lg * 8);

    f32x4 accL[4] = {}, accH[4] = {};
    float liL = 0.f, liH = 0.f;

    auto stage = [&](int n) {            // 4 global_load_lds per wave
        const int kn = n * 64;
        bf16* kd = Ks[n & 3];
        bf16* vd = Vs[n & 3];
        #pragma unroll
        for (int i = 0; i < 2; ++i) {
            const int kc  = i * 4 + lg;
            const int kcv = i * 4 + sg;  // sigma-permuted V source (LDS linear)
            async16(Kp + (size_t)(kn + srow) * DK_ + kc * 8,
                    kd + (i * 256 + wave * 64) * 8);
            async16(Vt + (size_t)srow * S_ + kn + kcv * 8,
                    vd + (i * 256 + wave * 64) * 8);
        }
    };

    stage(0); stage(1); stage(2);        // prologue: 12 loads in flight

    for (int j = 0; j <= hi; ++j) {
        // Counted wait: tile j's 4 loads retired; tiles j+1, j+2 still in
        // flight (8 outstanding). Exact counts on the tail.
        if (j + 2 <= hi)      asm volatile("s_waitcnt vmcnt(8)" ::: "memory");
        else if (j + 1 <= hi) asm volatile("s_waitcnt vmcnt(4)" ::: "memory");
        else                  asm volatile("s_waitcnt vmcnt(0)" ::: "memory");
        __builtin_amdgcn_s_barrier();    // raw barrier: no vmcnt drain
        if (j + 3 <= hi) stage(j + 3);   // overwrites buf (j-1)&3: safe

        const bf16* ks = Ks[j & 3];
        const bf16* vs = Vs[j & 3];

        bf16x8 kf0[4], kf1[4], vf0[4], vf1[4];
        #pragma unroll
        for (int t = 0; t < 4; ++t) {
            kf0[t] = ldg8(&ks[(t * 64 + lane) * 8]);
            kf1[t] = ldg8(&ks[(256 + t * 64 + lane) * 8]);
            vf0[t] = ldg8(&vs[(t * 64 + lane) * 8]);
            vf1[t] = ldg8(&vs[(256 + t * 64 + lane) * 8]);
        }

        auto step = [&](const bf16x8& qf0, const bf16x8& qf1, bool diag,
                        f32x4* accO, float& li) {
            f32x4 st[4];
            #pragma unroll
            for (int t = 0; t < 4; ++t) {
                f32x4 zz = {};
                zz = MFMA16(kf0[t], qf0, zz);
                st[t] = MFMA16(kf1[t], qf1, zz);
            }
            float rs = 0.f;
            if (diag) {
                #pragma unroll
                for (int t = 0; t < 4; ++t)
                    #pragma unroll
                    for (int r = 0; r < 4; ++r) {
                        const int kl = t * 16 + lg * 4 + r;
                        const float pv = EXP2((kl <= mrow) ? st[t][r] : -1e30f);
                        st[t][r] = pv;
                        rs += pv;
                    }
            } else {
                #pragma unroll
                for (int t = 0; t < 4; ++t)
                    #pragma unroll
                    for (int r = 0; r < 4; ++r) {
                        const float pv = EXP2(st[t][r]);
                        st[t][r] = pv;
                        rs += pv;
                    }
            }
            li += rs;

            const bf16x8 p0 = pfrag(st[0], st[1]);   // k 0..31  (sigma order)
            const bf16x8 p1 = pfrag(st[2], st[3]);   // k 32..63 (sigma order)

            #pragma unroll
            for (int t = 0; t < 4; ++t) {
                accO[t] = MFMA16(vf0[t], p0, accO[t]);
                accO[t] = MFMA16(vf1[t], p1, accO[t]);
            }
        };

        step(qfH0, qfH1, j == hi, accH, liH);
        if (j <= lo) step(qfL0, qfL1, j == lo, accL, liL);
    }

    // ---- epilogue: frag-major ctx via per-wave LDS transpose ---------------
    liL += __shfl_xor(liL, 16); liL += __shfl_xor(liL, 32);
    liH += __shfl_xor(liH, 16); liH += __shfl_xor(liH, 32);
    const float rlL = 1.0f / liL;
    const float rlH = 1.0f / liH;
    __syncthreads();                     // full drain once; reuse Ks
    bf16* T = &Ks[0][0] + wave * 1280;   // 16 x 72 (padded) transpose buffer

    #pragma unroll
    for (int half = 0; half < 2; ++half) {
        const f32x4* accO = half ? accH : accL;
        const float rl = half ? rlH : rlL;
        const int jq = half ? hi : lo;
        #pragma unroll
        for (int t = 0; t < 4; ++t) {
            bf16x4 ov;
            #pragma unroll
            for (int r = 0; r < 4; ++r) ov[r] = (bf16)(accO[t][r] * rl);
            *reinterpret_cast<bf16x4*>(&T[lc * 72 + t * 16 + lg * 4]) = ov;
        }
        // wave-synchronous LDS: compiler inserts lgkmcnt before these reads
        #pragma unroll
        for (int kk = 0; kk < 2; ++kk) {
            bf16x8 o8 = ldg8(&T[lc * 72 + kk * 32 + lg * 8]);
            *reinterpret_cast<bf16x8*>(
                &CtxF[fragbase(b * 32 + jq, h, kk, wave) + (size_t)lane * 8]) = o8;
        }
    }
}

extern "C" void kernel_launch(void* const* d_in, const int* in_sizes, int n_in,
                              void* d_out, int out_size, void* d_ws, size_t ws_size,
                              hipStream_t stream)
{
    float* out = (float*)d_out;

    bf16* Xf   = (bf16*)d_ws;                         // [3][M_*D_] frag-major
    bf16* Wf   = Xf + (size_t)3 * M_ * D_;            // [4][D_*D_] frag-major
    bf16* qkv  = Wf + (size_t)4 * D_ * D_;            // Q,K [bh][s][64]; V^T [bh][d][s]
    bf16* ctxF = qkv + (size_t)3 * M_ * D_;           // [M_*D_] frag-major

    cvt_all<<<6656, 256, 0, stream>>>(
        (const float*)d_in[0], (const float*)d_in[1], (const float*)d_in[2],
        (const float*)d_in[3], (const float*)d_in[4], (const float*)d_in[5],
        (const float*)d_in[6], Xf);

    gemm_qkv<<<dim3(768), 256, 0, stream>>>(Xf, Wf, qkv);
    attn<<<dim3(512), 256, 0, stream>>>(qkv, ctxF);
    gemm_out<<<dim3(512), 256, 0, stream>>>(ctxF, Wf + (size_t)3 * D_ * D_, out);
}

// Round 5
// 174.680 us; speedup vs baseline: 1.0850x; 1.0611x over previous
//
#include <hip/hip_runtime.h>
#include <hip/hip_bf16.h>
#include <math.h>

#define B_  4
#define S_  2048
#define D_  512
#define H_  8
#define DK_ 64
#define M_  (B_ * S_)   // 8192

using bf16   = __bf16;
using bf16x4 = __bf16 __attribute__((ext_vector_type(4)));
using bf16x8 = __bf16 __attribute__((ext_vector_type(8)));
using f32x4  = float __attribute__((ext_vector_type(4)));

#define MFMA16(a, b, c) __builtin_amdgcn_mfma_f32_16x16x32_bf16((a), (b), (c), 0, 0, 0)
#define EXP2(x) exp2f(x)

typedef __attribute__((address_space(3))) void       lds_void;
typedef const __attribute__((address_space(1))) void gbl_void;

__device__ __forceinline__ void async16(const bf16* g, bf16* lds) {
    __builtin_amdgcn_global_load_lds((gbl_void*)g, (lds_void*)lds, 16, 0, 0);
}

__device__ __forceinline__ bf16x8 ldg8(const bf16* p) {
    return *reinterpret_cast<const bf16x8*>(p);
}

// Fragment-major layout for a [R x 512] matrix (rows = MFMA m/n dim, cols = K):
// chunk(g,k0,kk,t) holds rows g*64+t*16+{0..15}, cols k0*64+kk*32+{0..31};
// lane = (k_sub>>3)*16 + (row&15), 8 bf16 per lane. One ldg8 at base+lane*8 is
// a fully-coalesced 1 KB read in exact MFMA A/B fragment order.
__device__ __forceinline__ size_t fragbase(int g, int k0, int kk, int t) {
    return ((((size_t)(g * 8 + k0) * 2 + kk) * 4 + t) * 64) * 8;
}

// ---------------------------------------------------------------------------
// Fused f32->bf16 conversion + fragment-major re-layout for all 7 tensors.
// One WAVE per 1 KB fragment chunk: dst = base + c*512 + lane*8 is exactly
// linear (fully-coalesced 16 B/lane stores); src gathers 16 rows x 32 B
// (128 B-coalescible across the lg groups).
// ---------------------------------------------------------------------------
__global__ __launch_bounds__(256) void cvt_all(
    const float* __restrict__ x0, const float* __restrict__ x1, const float* __restrict__ x2,
    const float* __restrict__ w0, const float* __restrict__ w1,
    const float* __restrict__ w2, const float* __restrict__ w3,
    bf16* __restrict__ dst)
{
    const int w    = blockIdx.x * 4 + (threadIdx.x >> 6);  // wave id, 0..26623
    const int lane = threadIdx.x & 63;
    const int lg = lane >> 4, lc = lane & 15;
    const float* src;
    int c;
    size_t dbase;
    if (w < 24576) {                                       // X tensors: 3 x 8192 chunks
        const int seg = w >> 13;
        c = w & 8191;
        src = (seg == 0) ? x0 : (seg == 1) ? x1 : x2;
        dbase = (size_t)seg << 22;
    } else {                                               // W tensors: 4 x 512 chunks
        const int jj = w - 24576;
        const int seg = jj >> 9;
        c = jj & 511;
        src = (seg == 0) ? w0 : (seg == 1) ? w1 : (seg == 2) ? w2 : w3;
        dbase = ((size_t)3 << 22) + ((size_t)seg << 18);
    }
    // c = ((g*8+k0)*2+kk)*4+t  (matches fragbase ordering)
    const int g = c >> 6, k0 = (c >> 3) & 7, kk = (c >> 2) & 1, t = c & 3;
    const size_t soff = ((size_t)(g * 64 + t * 16 + lc) << 9) + k0 * 64 + kk * 32 + lg * 8;
    f32x4 a = *reinterpret_cast<const f32x4*>(src + soff);
    f32x4 b = *reinterpret_cast<const f32x4*>(src + soff + 4);
    bf16x8 r;
    #pragma unroll
    for (int j = 0; j < 4; ++j) { r[j] = (bf16)a[j]; r[j + 4] = (bf16)b[j]; }
    *reinterpret_cast<bf16x8*>(dst + dbase + ((size_t)c << 9) + (size_t)lane * 8) = r;
}

// ---------------------------------------------------------------------------
// QKV projection, LDS-FREE: both operands read as coalesced fragment loads
// straight from L2 (frag-major buffers). No __shared__, no barriers — the
// k-loop is pure load->MFMA, compiler-pipelined with vmcnt.
// z<2 (Q,K): A=W (m=d), B=X (n=s) -> C-regs along d, packed bf16x4 stores to
//   [z][bh][s][64]; z==0 folds 0.125*log2e. z==2 (V): A=X, B=W -> V^T store.
// Grid 768; XCD-aware decode keeps an X m-stripe on one XCD.
// ---------------------------------------------------------------------------
__global__ __launch_bounds__(256) void gemm_qkv(
    const bf16* __restrict__ Xf, const bf16* __restrict__ Wf,
    bf16* __restrict__ qkv)
{
    const int bx  = blockIdx.x;
    const int xcd = bx & 7;
    const int idx = bx >> 3;
    const int mt  = xcd + 8 * (idx & 7);       // 0..63: X 128-row tile
    const int rest = idx >> 3;
    const int nt  = rest & 3;                  // 0..3: W 128-row tile
    const int z   = rest >> 2;                 // 0..2

    const bf16* Xz = Xf + (size_t)z * M_ * D_;
    const bf16* Wz = Wf + (size_t)z * D_ * D_;
    const bool vz = (z == 2);
    const bf16* A  = vz ? Xz : Wz;             // MFMA-A operand (m rows)
    const bf16* Bm = vz ? Wz : Xz;             // MFMA-B operand (n rows)

    const int lane = threadIdx.x & 63;
    const int wave = threadIdx.x >> 6;
    const int lc = lane & 15;
    const int lg = lane >> 4;
    const int gA = (vz ? 2 * mt : 2 * nt) + (wave >> 1);
    const int gB = (vz ? 2 * nt : 2 * mt) + (wave & 1);

    f32x4 acc[4][4] = {};

    #pragma unroll
    for (int k0 = 0; k0 < 8; ++k0) {
        #pragma unroll
        for (int kk = 0; kk < 2; ++kk) {
            bf16x8 af[4], bfm[4];
            #pragma unroll
            for (int t = 0; t < 4; ++t)
                af[t] = ldg8(A + fragbase(gA, k0, kk, t) + (size_t)lane * 8);
            #pragma unroll
            for (int t = 0; t < 4; ++t)
                bfm[t] = ldg8(Bm + fragbase(gB, k0, kk, t) + (size_t)lane * 8);
            #pragma unroll
            for (int mi = 0; mi < 4; ++mi)
                #pragma unroll
                for (int ni = 0; ni < 4; ++ni)
                    acc[mi][ni] = MFMA16(af[mi], bfm[ni], acc[mi][ni]);
        }
    }

    if (z < 2) {
        bf16* Y = qkv + (size_t)z * M_ * D_;
        const float sc = (z == 0) ? 0.125f * 1.4426950408889634f : 1.0f;
        #pragma unroll
        for (int mi = 0; mi < 4; ++mi)
            #pragma unroll
            for (int ni = 0; ni < 4; ++ni) {
                const int d = gA * 64 + mi * 16 + lg * 4;
                const int s = gB * 64 + ni * 16 + lc;
                bf16x4 v;
                #pragma unroll
                for (int r = 0; r < 4; ++r) v[r] = (bf16)(acc[mi][ni][r] * sc);
                const size_t oidx =
                    ((((size_t)(s >> 11) * H_ + (d >> 6)) * S_
                      + (s & (S_ - 1))) << 6) + (d & 63);
                *reinterpret_cast<bf16x4*>(&Y[oidx]) = v;
            }
    } else {
        bf16* Y = qkv + (size_t)2 * M_ * D_;
        #pragma unroll
        for (int mi = 0; mi < 4; ++mi)
            #pragma unroll
            for (int ni = 0; ni < 4; ++ni) {
                const int s = gA * 64 + mi * 16 + lg * 4;
                const int d = gB * 64 + ni * 16 + lc;
                bf16x4 v;
                #pragma unroll
                for (int r = 0; r < 4; ++r) v[r] = (bf16)acc[mi][ni][r];
                const size_t oidx =
                    ((((size_t)(s >> 11)) * H_ + (d >> 6)) << 17)
                    + (size_t)(d & 63) * S_ + (s & (S_ - 1));
                *reinterpret_cast<bf16x4*>(&Y[oidx]) = v;
            }
    }
}

// ---------------------------------------------------------------------------
// Output projection, LDS-free: A=Wo frag (m=d), B=ctx frag (n=s).
// Block = 64 s-rows x 128 d-cols, 4 waves (each 64d x 64s via 2 a-tiles).
// Grid 512 (2 blocks/CU), XCD swizzle on the s-stripe.
// ---------------------------------------------------------------------------
__global__ __launch_bounds__(256) void gemm_out(
    const bf16* __restrict__ CtxF, const bf16* __restrict__ WoF,
    float* __restrict__ out)
{
    const int bx  = blockIdx.x;
    const int xcd = bx & 7;
    const int idx = bx >> 3;
    const int mt  = xcd + 8 * (idx & 15);      // 0..127: ctx 64-row s-group
    const int nt  = idx >> 4;                  // 0..3: Wo 128-row d-tile

    const int lane = threadIdx.x & 63;
    const int wave = threadIdx.x >> 6;
    const int lc = lane & 15;
    const int lg = lane >> 4;
    const int gA = 2 * nt + (wave >> 1);       // Wo 64-row group
    const int tA = (wave & 1) * 2;             // 2 d-tiles per wave
    const int gB = mt;                         // ctx s-group (shared by block)

    f32x4 acc[2][4] = {};

    #pragma unroll
    for (int k0 = 0; k0 < 8; ++k0) {
        #pragma unroll
        for (int kk = 0; kk < 2; ++kk) {
            bf16x8 af[2], bfm[4];
            #pragma unroll
            for (int ai = 0; ai < 2; ++ai)
                af[ai] = ldg8(WoF + fragbase(gA, k0, kk, tA + ai) + (size_t)lane * 8);
            #pragma unroll
            for (int t = 0; t < 4; ++t)
                bfm[t] = ldg8(CtxF + fragbase(gB, k0, kk, t) + (size_t)lane * 8);
            #pragma unroll
            for (int ai = 0; ai < 2; ++ai)
                #pragma unroll
                for (int ni = 0; ni < 4; ++ni)
                    acc[ai][ni] = MFMA16(af[ai], bfm[ni], acc[ai][ni]);
        }
    }

    #pragma unroll
    for (int ai = 0; ai < 2; ++ai)
        #pragma unroll
        for (int ni = 0; ni < 4; ++ni) {
            const int d = gA * 64 + (tA + ai) * 16 + lg * 4;
            const int s = gB * 64 + ni * 16 + lc;
            *reinterpret_cast<f32x4*>(&out[(size_t)s * D_ + d]) = acc[ai][ni];
        }
}

// ---------------------------------------------------------------------------
// Build the PV B-fragment IN REGISTERS from the QK^T score layout.
// Scores: lane(lg,lc) holds P[k=16t+4lg+r][q=lc] (r=0..3) per t.
// bf16-pack pairs into dwords, then one permlane16_swap per dword pair:
// dst.row[2k+1] <-> src.row[2k]. Result rows hold k-chunks in order
// sigma=[0,2,1,3]; V's LDS staging is source-permuted with the same sigma
// (T21: per-lane global src permutation, linear LDS, linear b128 reads).
// Must be the BUILTIN, not inline asm (hazard recognizer).
// ---------------------------------------------------------------------------
__device__ __forceinline__ bf16x8 pfrag(const f32x4 a, const f32x4 b) {
    union U4 { bf16x4 v; unsigned int u[2]; };
    U4 pa, pb;
    #pragma unroll
    for (int r = 0; r < 4; ++r) { pa.v[r] = (bf16)a[r]; pb.v[r] = (bf16)b[r]; }
    auto r0 = __builtin_amdgcn_permlane16_swap(pa.u[0], pb.u[0], false, false);
    auto r1 = __builtin_amdgcn_permlane16_swap(pa.u[1], pb.u[1], false, false);
    union U8 { unsigned int u[4]; bf16x8 v; } out;
    out.u[0] = r0[0]; out.u[1] = r1[0]; out.u[2] = r0[1]; out.u[3] = r1[1];
    return out.v;
}

// ---------------------------------------------------------------------------
// Causal flash attention (max-free softmax — scores bounded by construction).
// 8-WAVE paired-tile blocks: waves 0-3 own the hi tile's 4 row-groups, waves
// 4-7 own the lo tile's — ONE step per wave per iteration. r4 showed per-iter
// wall ~3.8k cyc vs ~0.5k cyc of throughput need: latency-bound on the
// QK->exp2->pack->PV serial chain with only 2 waves/SIMD. This halves the
// per-wave chain and doubles waves/SIMD (2 blocks/CU x 8 waves = 4/SIMD).
// Pipeline unchanged (verified r4): 4-deep K/V ring, raw s_barrier + counted
// vmcnt (2 loads/wave/stage -> vmcnt(4)/(2)/(0)), stage(j+3) after barrier
// overwrites buf (j-1)&3 whose readers all passed the barrier.
// P never touches LDS (permlane16_swap + sigma-permuted V staging).
// Q pre-scaled by 0.125*log2e (folded into its projection).
// ---------------------------------------------------------------------------
__global__ __launch_bounds__(512, 4) void attn(
    const bf16* __restrict__ QKV, bf16* __restrict__ CtxF)
{
    const int bx = blockIdx.x;
    const int bh = (bx & 7) * 4 + ((bx >> 3) & 3);   // same-XCD bh grouping
    const int pi = bx >> 5;                           // 0..15
    const int b = bh >> 3, h = bh & 7;
    const size_t plane = (size_t)S_ * DK_;
    const bf16* Q  = QKV + (size_t)bh * plane;
    const bf16* Kp = QKV + (size_t)(B_ * H_) * plane + (size_t)bh * plane;
    const bf16* Vt = QKV + 2 * (size_t)(B_ * H_) * plane + (size_t)bh * plane;

    const int lane = threadIdx.x & 63;
    const int wave = threadIdx.x >> 6;   // 0..7
    const int wv   = wave & 3;           // row-group within tile
    const int half = wave >> 2;          // 0 -> hi tile, 1 -> lo tile
    const int lc = lane & 15;
    const int lg = lane >> 4;
    const int sg = ((lg & 1) << 1) | (lg >> 1);      // sigma(lg): swap 1<->2
    const int srow = wv * 16 + lc;
    const int mrow = wv * 16 + lc;       // q row within tile for this lane

    __shared__ bf16 Ks[4][64 * 64];      // 4-deep ring, 32 KB
    __shared__ bf16 Vs[4][64 * 64];      // 4-deep ring, 32 KB

    const int lo = pi;
    const int hi = 31 - pi;              // hi >= 16 always
    const int myq = half ? lo : hi;      // this wave's q-tile

    const int qR = myq * 64 + mrow;
    bf16x8 qf0 = ldg8(Q + (size_t)qR * DK_ + lg * 8);
    bf16x8 qf1 = ldg8(Q + (size_t)qR * DK_ + 32 + lg * 8);

    f32x4 accO[4] = {};
    float li = 0.f;

    // Staging split: waves 0-3 stage K, waves 4-7 stage V (2 async16/wave,
    // 16 KB/tile block-total; LDS dst identical to the 4-wave layout).
    auto stage = [&](int n) {
        const int kn = n * 64;
        if (half == 0) {
            bf16* kd = Ks[n & 3];
            #pragma unroll
            for (int i = 0; i < 2; ++i) {
                const int kc = i * 4 + lg;
                async16(Kp + (size_t)(kn + srow) * DK_ + kc * 8,
                        kd + (i * 256 + wv * 64) * 8);
            }
        } else {
            bf16* vd = Vs[n & 3];
            #pragma unroll
            for (int i = 0; i < 2; ++i) {
                const int kcv = i * 4 + sg;  // sigma-permuted V source
                async16(Vt + (size_t)srow * S_ + kn + kcv * 8,
                        vd + (i * 256 + wv * 64) * 8);
            }
        }
    };

    stage(0); stage(1); stage(2);        // prologue: 6 loads in flight / wave

    for (int j = 0; j <= hi; ++j) {
        // Counted wait: this wave's tile-j loads retired; j+1, j+2 in flight.
        if (j + 2 <= hi)      asm volatile("s_waitcnt vmcnt(4)" ::: "memory");
        else if (j + 1 <= hi) asm volatile("s_waitcnt vmcnt(2)" ::: "memory");
        else                  asm volatile("s_waitcnt vmcnt(0)" ::: "memory");
        __builtin_amdgcn_s_barrier();    // raw barrier: no vmcnt drain
        if (j + 3 <= hi) stage(j + 3);   // overwrites buf (j-1)&3: safe

        if (j <= myq) {                  // lo-tile waves idle (stage-only) past lo
            const bf16* ks = Ks[j & 3];
            const bf16* vs = Vs[j & 3];

            bf16x8 kf0[4], kf1[4], vf0[4], vf1[4];
            #pragma unroll
            for (int t = 0; t < 4; ++t) {
                kf0[t] = ldg8(&ks[(t * 64 + lane) * 8]);
                kf1[t] = ldg8(&ks[(256 + t * 64 + lane) * 8]);
                vf0[t] = ldg8(&vs[(t * 64 + lane) * 8]);
                vf1[t] = ldg8(&vs[(256 + t * 64 + lane) * 8]);
            }

            f32x4 st[4];
            #pragma unroll
            for (int t = 0; t < 4; ++t) {
                f32x4 zz = {};
                zz = MFMA16(kf0[t], qf0, zz);
                st[t] = MFMA16(kf1[t], qf1, zz);
            }
            float rs = 0.f;
            if (j == myq) {              // diagonal tile: causal mask
                #pragma unroll
                for (int t = 0; t < 4; ++t)
                    #pragma unroll
                    for (int r = 0; r < 4; ++r) {
                        const int kl = t * 16 + lg * 4 + r;
                        const float pv = EXP2((kl <= mrow) ? st[t][r] : -1e30f);
                        st[t][r] = pv;
                        rs += pv;
                    }
            } else {
                #pragma unroll
                for (int t = 0; t < 4; ++t)
                    #pragma unroll
                    for (int r = 0; r < 4; ++r) {
                        const float pv = EXP2(st[t][r]);
                        st[t][r] = pv;
                        rs += pv;
                    }
            }
            li += rs;

            const bf16x8 p0 = pfrag(st[0], st[1]);   // k 0..31  (sigma order)
            const bf16x8 p1 = pfrag(st[2], st[3]);   // k 32..63 (sigma order)

            #pragma unroll
            for (int t = 0; t < 4; ++t) {
                accO[t] = MFMA16(vf0[t], p0, accO[t]);
                accO[t] = MFMA16(vf1[t], p1, accO[t]);
            }
        }
    }

    // ---- epilogue: frag-major ctx via per-wave LDS transpose ---------------
    li += __shfl_xor(li, 16); li += __shfl_xor(li, 32);
    const float rl = 1.0f / li;
    __syncthreads();                     // full drain once; reuse Ks
    bf16* T = &Ks[0][0] + wave * 1280;   // 8 waves x 16x72 (padded) buffers

    #pragma unroll
    for (int t = 0; t < 4; ++t) {
        bf16x4 ov;
        #pragma unroll
        for (int r = 0; r < 4; ++r) ov[r] = (bf16)(accO[t][r] * rl);
        *reinterpret_cast<bf16x4*>(&T[lc * 72 + t * 16 + lg * 4]) = ov;
    }
    // wave-synchronous LDS: compiler inserts lgkmcnt before these reads
    #pragma unroll
    for (int kk = 0; kk < 2; ++kk) {
        bf16x8 o8 = ldg8(&T[lc * 72 + kk * 32 + lg * 8]);
        *reinterpret_cast<bf16x8*>(
            &CtxF[fragbase(b * 32 + myq, h, kk, wv) + (size_t)lane * 8]) = o8;
    }
}

extern "C" void kernel_launch(void* const* d_in, const int* in_sizes, int n_in,
                              void* d_out, int out_size, void* d_ws, size_t ws_size,
                              hipStream_t stream)
{
    float* out = (float*)d_out;

    bf16* Xf   = (bf16*)d_ws;                         // [3][M_*D_] frag-major
    bf16* Wf   = Xf + (size_t)3 * M_ * D_;            // [4][D_*D_] frag-major
    bf16* qkv  = Wf + (size_t)4 * D_ * D_;            // Q,K [bh][s][64]; V^T [bh][d][s]
    bf16* ctxF = qkv + (size_t)3 * M_ * D_;           // [M_*D_] frag-major

    cvt_all<<<6656, 256, 0, stream>>>(
        (const float*)d_in[0], (const float*)d_in[1], (const float*)d_in[2],
        (const float*)d_in[3], (const float*)d_in[4], (const float*)d_in[5],
        (const float*)d_in[6], Xf);

    gemm_qkv<<<dim3(768), 256, 0, stream>>>(Xf, Wf, qkv);
    attn<<<dim3(512), 512, 0, stream>>>(qkv, ctxF);
    gemm_out<<<dim3(512), 256, 0, stream>>>(ctxF, Wf + (size_t)3 * D_ * D_, out);
}